// Round 2
// baseline (409.208 us; speedup 1.0000x reference)
//
#include <hip/hip_runtime.h>
#include <math.h>

#define NROWS 131072
#define HID 256
#define NPAR 800
#define MROWS 64
#define NTHREADS 512
#define NBLOCKS (NROWS / MROWS)      // 2048

#define W2F_FRAGS 25600              // 50 col-tiles * 8 k-steps * 64 lanes
#define LDS_HLO 32768
#define LDS_P   65536
#define LDS_TOTAL 116864             // 2*32768 + 32*401*4

typedef __attribute__((ext_vector_type(8))) short s16x8;
typedef __attribute__((ext_vector_type(4))) float f32x4;

__device__ __forceinline__ unsigned short bf16_rne(float f) {
    unsigned u = __float_as_uint(f);
    u += 0x7fffu + ((u >> 16) & 1u);
    return (unsigned short)(u >> 16);
}

// Pre-split W2 (fp32 [256][800]) into bf16 hi/lo fragments, hi/lo PAIRED per lane
// (32B contiguous per lane) in per-lane MFMA B-operand order:
//   pair g = ct*8+k0; lane l holds 8 bf16 = W2[k0*32 + (l>>4)*8 + j][ct*16 + (l&15)]
//   hi at frag index g*128 + l*2, lo at g*128 + l*2 + 1   (s16x8 units)
__global__ void prep_w2(const float* __restrict__ W2, short* __restrict__ wsp)
{
    const int t = blockIdx.x * 256 + threadIdx.x;
    if (t >= W2F_FRAGS) return;
    const int l = t & 63;
    const int g = t >> 6;
    const int ct = g >> 3, k0 = g & 7;
    const int c  = (ct << 4) + (l & 15);
    const int kb = (k0 << 5) + ((l >> 4) << 3);
    s16x8 hi, lo;
#pragma unroll
    for (int j = 0; j < 8; ++j) {
        float v = W2[(size_t)(kb + j) * NPAR + c];
        unsigned short h = bf16_rne(v);
        float hf = __uint_as_float((unsigned)h << 16);
        unsigned short lw = bf16_rne(v - hf);
        hi[j] = (short)h;
        lo[j] = (short)lw;
    }
    ((s16x8*)wsp)[g * 128 + l * 2]     = hi;
    ((s16x8*)wsp)[g * 128 + l * 2 + 1] = lo;
}

__global__ __launch_bounds__(NTHREADS, 2)
void rqs_fused(const float* __restrict__ inp,
               const float* __restrict__ W1,
               const float* __restrict__ b1,
               const short* __restrict__ W2F,
               const float* __restrict__ b2,
               float* __restrict__ out)
{
    extern __shared__ char smem[];
    char*  hhi   = smem;                       // [64][256] bf16, XOR-swizzled
    char*  hlo   = smem + LDS_HLO;             // [64][256] bf16, XOR-swizzled
    float* p_lds = (float*)(smem + LDS_P);     // [32][401] fp32 param staging
    float* x_lds = (float*)(smem + LDS_P);     // [64][32] fp32 x_id (aliased, dead before p_lds use)

    const int t    = threadIdx.x;
    const int row0 = blockIdx.x * MROWS;
    const int lane = t & 63;
    const int w    = t >> 6;                   // wave id 0..7
    const int arow = lane & 15;
    const int kgrp = lane >> 4;

    const s16x8* BF = (const s16x8*)W2F;
    const int lane2 = lane << 1;

    // ---- GEMM2 B prologue: issue steps 0..2 (k0=0, ci=0..2) before anything waits ----
    s16x8 bh[4], bl[4];
    {
        const int fb0 = (w * 8) * 128;           // ct=w
        const int fb1 = ((w + 8) * 8) * 128;     // ct=w+8
        const int fb2 = ((w + 16) * 8) * 128;    // ct=w+16  (max 23 < 50)
        bh[0] = BF[fb0 + lane2]; bl[0] = BF[fb0 + lane2 + 1];
        bh[1] = BF[fb1 + lane2]; bl[1] = BF[fb1 + lane2 + 1];
        bh[2] = BF[fb2 + lane2]; bl[2] = BF[fb2 + lane2 + 1];
    }

    // ---- identity pass-through + x_id -> LDS: 64 rows x 8 float4, one per thread ----
    {
        const int r = t >> 3, q = t & 7;
        const float4 v = ((const float4*)(inp + (size_t)(row0 + r) * 64))[q];
        ((float4*)(out + (size_t)(row0 + r) * 64))[q] = v;
        ((float4*)(x_lds + r * 32))[q] = v;
    }
    __syncthreads();

    // ---- GEMM1: h = relu(x_id @ W1 + b1) from LDS; split to bf16 hi/lo in LDS ----
    {
        const int j  = t & 255;
        const int rh = __builtin_amdgcn_readfirstlane(t >> 8);   // wave-uniform row half
        float w1v[32];
#pragma unroll
        for (int k = 0; k < 32; ++k) w1v[k] = W1[k * HID + j];
        const float bj = b1[j];
        for (int rr = 0; rr < 32; ++rr) {
            const int r = rh * 32 + rr;
            const float4* xr = (const float4*)(x_lds + r * 32);  // uniform -> broadcast
            float s0 = bj, s1 = 0.f, s2 = 0.f, s3 = 0.f;
#pragma unroll
            for (int q = 0; q < 8; ++q) {
                const float4 xv = xr[q];
                s0 = fmaf(xv.x, w1v[4 * q + 0], s0);
                s1 = fmaf(xv.y, w1v[4 * q + 1], s1);
                s2 = fmaf(xv.z, w1v[4 * q + 2], s2);
                s3 = fmaf(xv.w, w1v[4 * q + 3], s3);
            }
            const float s = fmaxf((s0 + s1) + (s2 + s3), 0.0f);
            unsigned short hs = bf16_rne(s);
            float hf = __uint_as_float((unsigned)hs << 16);
            unsigned short ls = bf16_rne(s - hf);
            int byte = (r << 9) + (j << 1);
            byte ^= (r & 7) << 4;                                // bank swizzle
            *(short*)(hhi + byte) = (short)hs;
            *(short*)(hlo + byte) = (short)ls;
        }
    }
    __syncthreads();

    // ---- GEMM2: 56-step flattened pipeline, 4-deep B prefetch ----
    // step s: ci = s%7, k0 = s/7; all waves run 7 ct-slots (ct>=50 wraps, discarded later)
    f32x4 acc[7][4];
#pragma unroll
    for (int ci = 0; ci < 7; ++ci)
#pragma unroll
        for (int rt = 0; rt < 4; ++rt)
            acc[ci][rt] = (f32x4){0.f, 0.f, 0.f, 0.f};

    s16x8 ahi[4], alo[4];

#pragma unroll
    for (int s = 0; s < 56; ++s) {
        const int ci = s % 7, k0 = s / 7;

        // issue loads for step s+3 into stage (s+3)&3
        if (s + 3 < 56) {
            const int cn = (s + 3) % 7, kn = (s + 3) / 7;
            int ctn = w + cn * 8;
            if (ctn >= 50) ctn -= 50;               // wave-uniform wrap
            const int fb = (ctn * 8 + kn) * 128;
            bh[(s + 3) & 3] = BF[fb + lane2];
            bl[(s + 3) & 3] = BF[fb + lane2 + 1];
        }

        // A fragments at each k0 boundary
        if (ci == 0) {
#pragma unroll
            for (int rt = 0; rt < 4; ++rt) {
                const int row = rt * 16 + arow;
                int byte = (row << 9) + (k0 << 6) + (kgrp << 4);
                byte ^= (row & 7) << 4;
                ahi[rt] = *(const s16x8*)(hhi + byte);
                alo[rt] = *(const s16x8*)(hlo + byte);
            }
        }

        // 12 MFMAs on stage s&3
#pragma unroll
        for (int rt = 0; rt < 4; ++rt) {
            acc[ci][rt] = __builtin_amdgcn_mfma_f32_16x16x32_bf16(ahi[rt], bh[s & 3], acc[ci][rt], 0, 0, 0);
            acc[ci][rt] = __builtin_amdgcn_mfma_f32_16x16x32_bf16(ahi[rt], bl[s & 3], acc[ci][rt], 0, 0, 0);
            acc[ci][rt] = __builtin_amdgcn_mfma_f32_16x16x32_bf16(alo[rt], bh[s & 3], acc[ci][rt], 0, 0, 0);
        }
    }

    // ---- epilogue in 4 phases: (col-half 0/1) x (row-half 0/1); 512 threads = 32 rows x 16 d ----
    float lad_acc[2] = {0.f, 0.f};

#pragma unroll
    for (int chalf = 0; chalf < 2; ++chalf) {
#pragma unroll
        for (int rhalf = 0; rhalf < 2; ++rhalf) {
            __syncthreads();                                    // p_lds safe to overwrite
            const int c0 = chalf * 25;
#pragma unroll
            for (int ci = 0; ci < 7; ++ci) {
                const int ct = w + (ci << 3);
                if (ct < 50 && ct >= c0 && ct < c0 + 25) {
                    const float bias = b2[(ct << 4) + arow];
                    const int col = ((ct - c0) << 4) + arow;    // 0..399
#pragma unroll
                    for (int rr = 0; rr < 2; ++rr) {
                        const int rt = rhalf * 2 + rr;
                        const f32x4 v = acc[ci][rt];
                        const int rowl = (rr << 4) + (kgrp << 2);   // 0..31 (+reg)
                        p_lds[(rowl + 0) * 401 + col] = v[0] + bias;
                        p_lds[(rowl + 1) * 401 + col] = v[1] + bias;
                        p_lds[(rowl + 2) * 401 + col] = v[2] + bias;
                        p_lds[(rowl + 3) * 401 + col] = v[3] + bias;
                    }
                }
            }
            __syncthreads();

            // one (row, d) per thread
            {
                const int r_l = t >> 4;
                const int dl  = t & 15;
                const float* p = &p_lds[r_l * 401 + dl * 25];
                float pv[25];
#pragma unroll
                for (int j = 0; j < 25; ++j) pv[j] = p[j];

                float cw[9], ch[9], dd[9];
                {
                    float mw = pv[0];
#pragma unroll
                    for (int j = 1; j < 8; ++j) mw = fmaxf(mw, pv[j]);
                    float e[8], sw = 0.f;
#pragma unroll
                    for (int j = 0; j < 8; ++j) { e[j] = __expf(pv[j] - mw); sw += e[j]; }
                    const float scale = 0.992f / sw;
                    float run = 0.f;
                    cw[0] = 0.f;
#pragma unroll
                    for (int j = 0; j < 8; ++j) { run += 0.001f + e[j] * scale; cw[j + 1] = run; }
                    const float icn = 1.0f / fmaxf(cw[8], 1e-12f);
#pragma unroll
                    for (int j = 1; j <= 8; ++j) cw[j] *= icn;
                }
                {
                    float mh = pv[8];
#pragma unroll
                    for (int j = 1; j < 8; ++j) mh = fmaxf(mh, pv[8 + j]);
                    float e[8], sh = 0.f;
#pragma unroll
                    for (int j = 0; j < 8; ++j) { e[j] = __expf(pv[8 + j] - mh); sh += e[j]; }
                    const float scale = 0.992f / sh;
                    float run = 0.f;
                    ch[0] = 0.f;
#pragma unroll
                    for (int j = 0; j < 8; ++j) { run += 0.001f + e[j] * scale; ch[j + 1] = run; }
                    const float icn = 1.0f / fmaxf(ch[8], 1e-12f);
#pragma unroll
                    for (int j = 1; j <= 8; ++j) ch[j] *= icn;
                }
#pragma unroll
                for (int j = 0; j < 9; ++j) {
                    const float u = pv[16 + j];
                    dd[j] = 0.001f + fmaxf(u, 0.f) + log1pf(__expf(-fabsf(u)));
                }

                const int grow = row0 + rhalf * 32 + r_l;
                const int d = chalf * 16 + dl;
                const float x = inp[(size_t)grow * 64 + 32 + d];
                const float xs = fminf(fmaxf((x + 10.0f) * 0.05f, 0.f), 1.f);
                int b = 0;
#pragma unroll
                for (int j = 1; j <= 8; ++j) b += (xs >= cw[j]) ? 1 : 0;
                b = min(b, 7);

                float xk = 0.f, wk = 0.f, yk = 0.f, hk = 0.f, dk = 0.f, dk1 = 0.f;
#pragma unroll
                for (int j = 0; j < 8; ++j) {
                    if (b == j) {
                        xk = cw[j]; wk = cw[j + 1] - cw[j];
                        yk = ch[j]; hk = ch[j + 1] - ch[j];
                        dk = dd[j]; dk1 = dd[j + 1];
                    }
                }

                const float EPSf = 1e-12f;
                const float tt = fminf(fmaxf((xs - xk) / (wk + EPSf), 0.f), 1.f);
                const float a = (hk + EPSf) / (wk + EPSf);
                const float omt = 1.f - tt;
                const float tomt = tt * omt;
                const float num = a * tt * tt + dk * tomt;
                const float den = a + (dk + dk1 - 2.f * a) * tomt;
                const float sres = num / (den + EPSf);
                const float ys = yk + hk * sres;
                float y = ys * 20.0f - 10.0f;
                const float dnum = a * a * (dk1 * tt * tt + 2.f * a * tomt + dk * omt * omt);
                const float dydx = dnum / (den * den + EPSf);
                float lad = __logf(fmaxf(dydx, 1e-12f));

                const bool inside = (x >= -10.0f) && (x <= 10.0f);
                if (!inside) { y = x; lad = 0.0f; }

                out[(size_t)grow * 64 + 32 + d] = y;
                lad_acc[rhalf] += lad;
            }
        }
    }

    // ---- logabsdet: reduce 16 d-lanes per row (within-wave groups of 16) ----
    float s0 = lad_acc[0], s1 = lad_acc[1];
    s0 += __shfl_xor(s0, 1, 64); s0 += __shfl_xor(s0, 2, 64);
    s0 += __shfl_xor(s0, 4, 64); s0 += __shfl_xor(s0, 8, 64);
    s1 += __shfl_xor(s1, 1, 64); s1 += __shfl_xor(s1, 2, 64);
    s1 += __shfl_xor(s1, 4, 64); s1 += __shfl_xor(s1, 8, 64);
    if ((t & 15) == 0) {
        const int r_l = t >> 4;
        out[(size_t)NROWS * 64 + row0 + r_l]      = s0;
        out[(size_t)NROWS * 64 + row0 + 32 + r_l] = s1;
    }
}

extern "C" void kernel_launch(void* const* d_in, const int* in_sizes, int n_in,
                              void* d_out, int out_size, void* d_ws, size_t ws_size,
                              hipStream_t stream) {
    const float* inp = (const float*)d_in[0];
    const float* W1  = (const float*)d_in[1];
    const float* b1  = (const float*)d_in[2];
    const float* W2  = (const float*)d_in[3];
    const float* b2  = (const float*)d_in[4];
    float* out = (float*)d_out;
    short* wsp = (short*)d_ws;      // needs 819200 B for W2 hi/lo paired fragments

    static bool attr_done = false;
    if (!attr_done) {
        hipFuncSetAttribute((const void*)rqs_fused,
                            hipFuncAttributeMaxDynamicSharedMemorySize, LDS_TOTAL);
        attr_done = true;
    }

    hipLaunchKernelGGL(prep_w2, dim3(100), dim3(256), 0, stream, W2, wsp);
    hipLaunchKernelGGL(rqs_fused, dim3(NBLOCKS), dim3(NTHREADS), LDS_TOTAL, stream,
                       inp, W1, b1, (const short*)wsp, b2, out);
}

// Round 4
// 405.298 us; speedup vs baseline: 1.0096x; 1.0096x over previous
//
#include <hip/hip_runtime.h>
#include <math.h>

#define NROWS 131072
#define HID 256
#define NPAR 800
#define MROWS 64
#define NTHREADS 512
#define NBLOCKS (NROWS / MROWS)      // 2048

#define W2F_FRAGS 25600              // 50 col-tiles * 8 k-steps * 64 lanes
#define LDS_HLO 32768
#define LDS_P   65536
#define LDS_TOTAL 116864             // 2*32768 + 32*401*4

typedef __attribute__((ext_vector_type(8))) short s16x8;
typedef __attribute__((ext_vector_type(4))) float f32x4;

__device__ __forceinline__ unsigned short bf16_rne(float f) {
    unsigned u = __float_as_uint(f);
    u += 0x7fffu + ((u >> 16) & 1u);
    return (unsigned short)(u >> 16);
}

// Pre-split W2 (fp32 [256][800]) into bf16 hi/lo fragments, hi/lo PAIRED per lane
// (32B contiguous per lane) in per-lane MFMA B-operand order:
//   pair g = ct*8+k0; lane l holds 8 bf16 = W2[k0*32 + (l>>4)*8 + j][ct*16 + (l&15)]
//   hi at s16x8 index g*128 + l*2, lo at g*128 + l*2 + 1
__global__ void prep_w2(const float* __restrict__ W2, short* __restrict__ wsp)
{
    const int t = blockIdx.x * 256 + threadIdx.x;
    if (t >= W2F_FRAGS) return;
    const int l = t & 63;
    const int g = t >> 6;
    const int ct = g >> 3, k0 = g & 7;
    const int c  = (ct << 4) + (l & 15);
    const int kb = (k0 << 5) + ((l >> 4) << 3);
    s16x8 hi, lo;
#pragma unroll
    for (int j = 0; j < 8; ++j) {
        float v = W2[(size_t)(kb + j) * NPAR + c];
        unsigned short h = bf16_rne(v);
        float hf = __uint_as_float((unsigned)h << 16);
        unsigned short lw = bf16_rne(v - hf);
        hi[j] = (short)h;
        lo[j] = (short)lw;
    }
    ((s16x8*)wsp)[g * 128 + l * 2]     = hi;
    ((s16x8*)wsp)[g * 128 + l * 2 + 1] = lo;
}

__global__ __launch_bounds__(NTHREADS, 2)
void rqs_fused(const float* __restrict__ inp,
               const float* __restrict__ W1,
               const float* __restrict__ b1,
               const short* __restrict__ W2F,
               const float* __restrict__ b2,
               float* __restrict__ out)
{
    extern __shared__ char smem[];
    char*  hhi   = smem;                       // [64][256] bf16, XOR-swizzled
    char*  hlo   = smem + LDS_HLO;             // [64][256] bf16, XOR-swizzled
    float* p_lds = (float*)(smem + LDS_P);     // [32][401] fp32 param staging
    float* x_lds = (float*)(smem + LDS_P);     // [64][32] fp32 x_id (aliased, dead before p_lds use)

    const int t    = threadIdx.x;
    const int row0 = blockIdx.x * MROWS;
    const int lane = t & 63;
    const int w    = t >> 6;                   // wave id 0..7
    const int arow = lane & 15;
    const int kgrp = lane >> 4;
    const int lane2 = lane << 1;

    const s16x8* BF = (const s16x8*)W2F;

    // ---- identity pass-through + x_id -> LDS: 64 rows x 8 float4, one per thread ----
    {
        const int r = t >> 3, q = t & 7;
        const float4 v = ((const float4*)(inp + (size_t)(row0 + r) * 64))[q];
        ((float4*)(out + (size_t)(row0 + r) * 64))[q] = v;
        ((float4*)(x_lds + r * 32))[q] = v;
    }
    __syncthreads();

    // ---- GEMM1: h = relu(x_id @ W1 + b1) from LDS; split to bf16 hi/lo in LDS ----
    {
        const int j  = t & 255;
        const int rh = __builtin_amdgcn_readfirstlane(t >> 8);   // wave-uniform row half
        float w1v[32];
#pragma unroll
        for (int k = 0; k < 32; ++k) w1v[k] = W1[k * HID + j];
        const float bj = b1[j];
        for (int rr = 0; rr < 32; ++rr) {
            const int r = rh * 32 + rr;
            const float4* xr = (const float4*)(x_lds + r * 32);  // uniform -> broadcast
            float s0 = bj, s1 = 0.f, s2 = 0.f, s3 = 0.f;
#pragma unroll
            for (int q = 0; q < 8; ++q) {
                const float4 xv = xr[q];
                s0 = fmaf(xv.x, w1v[4 * q + 0], s0);
                s1 = fmaf(xv.y, w1v[4 * q + 1], s1);
                s2 = fmaf(xv.z, w1v[4 * q + 2], s2);
                s3 = fmaf(xv.w, w1v[4 * q + 3], s3);
            }
            const float s = fmaxf((s0 + s1) + (s2 + s3), 0.0f);
            unsigned short hs = bf16_rne(s);
            float hf = __uint_as_float((unsigned)hs << 16);
            unsigned short ls = bf16_rne(s - hf);
            int byte = (r << 9) + (j << 1);
            byte ^= (r & 7) << 4;                                // bank swizzle
            *(short*)(hhi + byte) = (short)hs;
            *(short*)(hlo + byte) = (short)ls;
        }
    }
    __syncthreads();

    // ---- GEMM2: statically-indexed MFMA loop (acc MUST stay in VGPRs) ----
    // wave w owns ct = w + 8*ci, ci = 0..nct-1 (nct = 7 for w<2 else 6), as in the
    // verified r2 epilogue mapping.
    const int nct = (w < 2) ? 7 : 6;

    f32x4 acc[7][4];
#pragma unroll
    for (int ci = 0; ci < 7; ++ci)
#pragma unroll
        for (int rt = 0; rt < 4; ++rt)
            acc[ci][rt] = (f32x4){0.f, 0.f, 0.f, 0.f};

#pragma unroll 1
    for (int k0 = 0; k0 < 8; ++k0) {
        // A fragments for this k0 (static arrays)
        s16x8 ahi[4], alo[4];
#pragma unroll
        for (int rt = 0; rt < 4; ++rt) {
            const int row = rt * 16 + arow;
            int byte = (row << 9) + (k0 << 6) + (kgrp << 4);
            byte ^= (row & 7) << 4;
            ahi[rt] = *(const s16x8*)(hhi + byte);
            alo[rt] = *(const s16x8*)(hlo + byte);
        }

        // B fragments for all 7 ci slots (static arrays; inactive slots load ct=w, discarded)
        s16x8 bh[7], bl[7];
#pragma unroll
        for (int ci = 0; ci < 7; ++ci) {
            int ct = w + (ci << 3);
            if (ct >= 50) ct = w;                // wave-uniform clamp, slot unused anyway
            const int f = (ct * 8 + k0) * 128 + lane2;
            bh[ci] = BF[f];
            bl[ci] = BF[f + 1];
        }

        // 84 (or 72) statically-indexed MFMAs
#pragma unroll
        for (int ci = 0; ci < 7; ++ci) {
            if (ci < nct) {
#pragma unroll
                for (int rt = 0; rt < 4; ++rt) {
                    acc[ci][rt] = __builtin_amdgcn_mfma_f32_16x16x32_bf16(ahi[rt], bh[ci], acc[ci][rt], 0, 0, 0);
                    acc[ci][rt] = __builtin_amdgcn_mfma_f32_16x16x32_bf16(ahi[rt], bl[ci], acc[ci][rt], 0, 0, 0);
                    acc[ci][rt] = __builtin_amdgcn_mfma_f32_16x16x32_bf16(alo[rt], bh[ci], acc[ci][rt], 0, 0, 0);
                }
            }
        }
    }

    // ---- epilogue in 4 phases: (col-half 0/1) x (row-half 0/1); 512 threads = 32 rows x 16 d ----
    float lad_acc[2] = {0.f, 0.f};

#pragma unroll
    for (int chalf = 0; chalf < 2; ++chalf) {
#pragma unroll
        for (int rhalf = 0; rhalf < 2; ++rhalf) {
            __syncthreads();                                    // p_lds safe to overwrite
            const int c0 = chalf * 25;
#pragma unroll
            for (int ci = 0; ci < 7; ++ci) {
                const int ct = w + (ci << 3);
                if (ci < nct && ct >= c0 && ct < c0 + 25) {
                    const float bias = b2[(ct << 4) + arow];
                    const int col = ((ct - c0) << 4) + arow;    // 0..399
#pragma unroll
                    for (int rr = 0; rr < 2; ++rr) {
                        const int rt = rhalf * 2 + rr;
                        const f32x4 v = acc[ci][rt];
                        const int rowl = (rr << 4) + (kgrp << 2);   // 0..31 (+reg)
                        p_lds[(rowl + 0) * 401 + col] = v[0] + bias;
                        p_lds[(rowl + 1) * 401 + col] = v[1] + bias;
                        p_lds[(rowl + 2) * 401 + col] = v[2] + bias;
                        p_lds[(rowl + 3) * 401 + col] = v[3] + bias;
                    }
                }
            }
            __syncthreads();

            // one (row, d) per thread
            {
                const int r_l = t >> 4;
                const int dl  = t & 15;
                const float* p = &p_lds[r_l * 401 + dl * 25];
                float pv[25];
#pragma unroll
                for (int j = 0; j < 25; ++j) pv[j] = p[j];

                float cw[9], ch[9], dd[9];
                {
                    float mw = pv[0];
#pragma unroll
                    for (int j = 1; j < 8; ++j) mw = fmaxf(mw, pv[j]);
                    float e[8], sw = 0.f;
#pragma unroll
                    for (int j = 0; j < 8; ++j) { e[j] = __expf(pv[j] - mw); sw += e[j]; }
                    const float scale = 0.992f / sw;
                    float run = 0.f;
                    cw[0] = 0.f;
#pragma unroll
                    for (int j = 0; j < 8; ++j) { run += 0.001f + e[j] * scale; cw[j + 1] = run; }
                    const float icn = 1.0f / fmaxf(cw[8], 1e-12f);
#pragma unroll
                    for (int j = 1; j <= 8; ++j) cw[j] *= icn;
                }
                {
                    float mh = pv[8];
#pragma unroll
                    for (int j = 1; j < 8; ++j) mh = fmaxf(mh, pv[8 + j]);
                    float e[8], sh = 0.f;
#pragma unroll
                    for (int j = 0; j < 8; ++j) { e[j] = __expf(pv[8 + j] - mh); sh += e[j]; }
                    const float scale = 0.992f / sh;
                    float run = 0.f;
                    ch[0] = 0.f;
#pragma unroll
                    for (int j = 0; j < 8; ++j) { run += 0.001f + e[j] * scale; ch[j + 1] = run; }
                    const float icn = 1.0f / fmaxf(ch[8], 1e-12f);
#pragma unroll
                    for (int j = 1; j <= 8; ++j) ch[j] *= icn;
                }
#pragma unroll
                for (int j = 0; j < 9; ++j) {
                    const float u = pv[16 + j];
                    dd[j] = 0.001f + fmaxf(u, 0.f) + log1pf(__expf(-fabsf(u)));
                }

                const int grow = row0 + rhalf * 32 + r_l;
                const int d = chalf * 16 + dl;
                const float x = inp[(size_t)grow * 64 + 32 + d];
                const float xs = fminf(fmaxf((x + 10.0f) * 0.05f, 0.f), 1.f);
                int b = 0;
#pragma unroll
                for (int j = 1; j <= 8; ++j) b += (xs >= cw[j]) ? 1 : 0;
                b = min(b, 7);

                float xk = 0.f, wk = 0.f, yk = 0.f, hk = 0.f, dk = 0.f, dk1 = 0.f;
#pragma unroll
                for (int j = 0; j < 8; ++j) {
                    if (b == j) {
                        xk = cw[j]; wk = cw[j + 1] - cw[j];
                        yk = ch[j]; hk = ch[j + 1] - ch[j];
                        dk = dd[j]; dk1 = dd[j + 1];
                    }
                }

                const float EPSf = 1e-12f;
                const float tt = fminf(fmaxf((xs - xk) / (wk + EPSf), 0.f), 1.f);
                const float a = (hk + EPSf) / (wk + EPSf);
                const float omt = 1.f - tt;
                const float tomt = tt * omt;
                const float num = a * tt * tt + dk * tomt;
                const float den = a + (dk + dk1 - 2.f * a) * tomt;
                const float sres = num / (den + EPSf);
                const float ys = yk + hk * sres;
                float y = ys * 20.0f - 10.0f;
                const float dnum = a * a * (dk1 * tt * tt + 2.f * a * tomt + dk * omt * omt);
                const float dydx = dnum / (den * den + EPSf);
                float lad = __logf(fmaxf(dydx, 1e-12f));

                const bool inside = (x >= -10.0f) && (x <= 10.0f);
                if (!inside) { y = x; lad = 0.0f; }

                out[(size_t)grow * 64 + 32 + d] = y;
                lad_acc[rhalf] += lad;
            }
        }
    }

    // ---- logabsdet: reduce 16 d-lanes per row (within-wave groups of 16) ----
    float s0 = lad_acc[0], s1 = lad_acc[1];
    s0 += __shfl_xor(s0, 1, 64); s0 += __shfl_xor(s0, 2, 64);
    s0 += __shfl_xor(s0, 4, 64); s0 += __shfl_xor(s0, 8, 64);
    s1 += __shfl_xor(s1, 1, 64); s1 += __shfl_xor(s1, 2, 64);
    s1 += __shfl_xor(s1, 4, 64); s1 += __shfl_xor(s1, 8, 64);
    if ((t & 15) == 0) {
        const int r_l = t >> 4;
        out[(size_t)NROWS * 64 + row0 + r_l]      = s0;
        out[(size_t)NROWS * 64 + row0 + 32 + r_l] = s1;
    }
}

extern "C" void kernel_launch(void* const* d_in, const int* in_sizes, int n_in,
                              void* d_out, int out_size, void* d_ws, size_t ws_size,
                              hipStream_t stream) {
    const float* inp = (const float*)d_in[0];
    const float* W1  = (const float*)d_in[1];
    const float* b1  = (const float*)d_in[2];
    const float* W2  = (const float*)d_in[3];
    const float* b2  = (const float*)d_in[4];
    float* out = (float*)d_out;
    short* wsp = (short*)d_ws;      // 819200 B for W2 hi/lo paired fragments

    static bool attr_done = false;
    if (!attr_done) {
        hipFuncSetAttribute((const void*)rqs_fused,
                            hipFuncAttributeMaxDynamicSharedMemorySize, LDS_TOTAL);
        attr_done = true;
    }

    hipLaunchKernelGGL(prep_w2, dim3(100), dim3(256), 0, stream, W2, wsp);
    hipLaunchKernelGGL(rqs_fused, dim3(NBLOCKS), dim3(NTHREADS), LDS_TOTAL, stream,
                       inp, W1, b1, (const short*)wsp, b2, out);
}

// Round 5
// 304.513 us; speedup vs baseline: 1.3438x; 1.3310x over previous
//
#include <hip/hip_runtime.h>
#include <math.h>

#define NROWS 131072
#define HID 256
#define NPAR 800
#define MROWS 64
#define NTHREADS 1024
#define NBLOCKS (NROWS / MROWS)      // 2048

#define W2F_FRAGS 25600              // 50 col-tiles * 8 k-steps * 64 lanes
#define LDS_HLO 32768
#define LDS_X   65536
#define LDS_TOTAL 102528             // p_lds [32][801] fp32 overlays everything

typedef __attribute__((ext_vector_type(8))) short s16x8;
typedef __attribute__((ext_vector_type(4))) float f32x4;

__device__ __forceinline__ unsigned short bf16_rne(float f) {
    unsigned u = __float_as_uint(f);
    u += 0x7fffu + ((u >> 16) & 1u);
    return (unsigned short)(u >> 16);
}

// Pre-split W2 (fp32 [256][800]) into bf16 hi/lo fragments, hi/lo PAIRED per lane
// (32B contiguous per lane) in per-lane MFMA B-operand order:
//   pair g = ct*8+k0; lane l holds 8 bf16 = W2[k0*32 + (l>>4)*8 + j][ct*16 + (l&15)]
//   hi at s16x8 index g*128 + l*2, lo at g*128 + l*2 + 1
__global__ void prep_w2(const float* __restrict__ W2, short* __restrict__ wsp)
{
    const int t = blockIdx.x * 256 + threadIdx.x;
    if (t >= W2F_FRAGS) return;
    const int l = t & 63;
    const int g = t >> 6;
    const int ct = g >> 3, k0 = g & 7;
    const int c  = (ct << 4) + (l & 15);
    const int kb = (k0 << 5) + ((l >> 4) << 3);
    s16x8 hi, lo;
#pragma unroll
    for (int j = 0; j < 8; ++j) {
        float v = W2[(size_t)(kb + j) * NPAR + c];
        unsigned short h = bf16_rne(v);
        float hf = __uint_as_float((unsigned)h << 16);
        unsigned short lw = bf16_rne(v - hf);
        hi[j] = (short)h;
        lo[j] = (short)lw;
    }
    ((s16x8*)wsp)[g * 128 + l * 2]     = hi;
    ((s16x8*)wsp)[g * 128 + l * 2 + 1] = lo;
}

__global__ __launch_bounds__(NTHREADS, 4)
void rqs_fused(const float* __restrict__ inp,
               const float* __restrict__ W1,
               const float* __restrict__ b1,
               const short* __restrict__ W2F,
               const float* __restrict__ b2,
               float* __restrict__ out)
{
    extern __shared__ char smem[];
    char*  hhi   = smem;                       // [64][256] bf16, XOR-swizzled (32 KB)
    char*  hlo   = smem + LDS_HLO;             // [64][256] bf16, XOR-swizzled (32 KB)
    float* x_lds = (float*)(smem + LDS_X);     // [64][32] fp32 x_id (8 KB)
    float* p_lds = (float*)smem;               // [32][801] fp32, overlays all (dead by then)

    const int t    = threadIdx.x;
    const int row0 = blockIdx.x * MROWS;
    const int lane = t & 63;
    const int w    = t >> 6;                   // wave id 0..15
    const int arow = lane & 15;
    const int kgrp = lane >> 4;
    const int lane2 = lane << 1;

    const s16x8* BF = (const s16x8*)W2F;

    // wave w owns ct = w + 16*ci; waves 0,1 have 4 tiles (ct up to 49), rest 3.
    const int nct = (w < 2) ? 4 : 3;

    // ---- identity pass-through + x_id -> LDS: 64 rows x 8 float4 (512 units) ----
    if (t < 512) {
        const int r = t >> 3, q = t & 7;
        const float4 v = ((const float4*)(inp + (size_t)(row0 + r) * 64))[q];
        ((float4*)(out + (size_t)(row0 + r) * 64))[q] = v;
        ((float4*)(x_lds + r * 32))[q] = v;
    }
    __syncthreads();

    // ---- GEMM1: h = relu(x_id @ W1 + b1); 4 thread-groups x 16 rows each ----
    {
        const int j = t & 255;                                   // hidden col
        const int q = t >> 8;                                    // row quarter (wave-uniform)
        float w1v[32];
#pragma unroll
        for (int k = 0; k < 32; ++k) w1v[k] = W1[k * HID + j];
        const float bj = b1[j];
        for (int rr = 0; rr < 16; ++rr) {
            const int r = q * 16 + rr;
            const float4* xr = (const float4*)(x_lds + r * 32);  // uniform -> broadcast
            float s0 = bj, s1 = 0.f, s2 = 0.f, s3 = 0.f;
#pragma unroll
            for (int qq = 0; qq < 8; ++qq) {
                const float4 xv = xr[qq];
                s0 = fmaf(xv.x, w1v[4 * qq + 0], s0);
                s1 = fmaf(xv.y, w1v[4 * qq + 1], s1);
                s2 = fmaf(xv.z, w1v[4 * qq + 2], s2);
                s3 = fmaf(xv.w, w1v[4 * qq + 3], s3);
            }
            const float s = fmaxf((s0 + s1) + (s2 + s3), 0.0f);
            unsigned short hs = bf16_rne(s);
            float hf = __uint_as_float((unsigned)hs << 16);
            unsigned short ls = bf16_rne(s - hf);
            int byte = (r << 9) + (j << 1);
            byte ^= (r & 7) << 4;                                // bank swizzle
            *(short*)(hhi + byte) = (short)hs;
            *(short*)(hlo + byte) = (short)ls;
        }
    }
    __syncthreads();

    // ---- GEMM2: 3-term bf16-split MFMA; acc[4][4] fits the 128-reg/4-wave budget ----
    f32x4 acc[4][4];
#pragma unroll
    for (int ci = 0; ci < 4; ++ci)
#pragma unroll
        for (int rt = 0; rt < 4; ++rt)
            acc[ci][rt] = (f32x4){0.f, 0.f, 0.f, 0.f};

#pragma unroll 1
    for (int k0 = 0; k0 < 8; ++k0) {
        s16x8 ahi[4], alo[4];
#pragma unroll
        for (int rt = 0; rt < 4; ++rt) {
            const int row = rt * 16 + arow;
            int byte = (row << 9) + (k0 << 6) + (kgrp << 4);
            byte ^= (row & 7) << 4;
            ahi[rt] = *(const s16x8*)(hhi + byte);
            alo[rt] = *(const s16x8*)(hlo + byte);
        }
#pragma unroll
        for (int ci = 0; ci < 4; ++ci) {
            if (ci < nct) {
                const int ct = w + (ci << 4);                    // max 49, no wrap
                const int f  = (ct * 8 + k0) * 128 + lane2;
                const s16x8 bh = BF[f];
                const s16x8 bl = BF[f + 1];
#pragma unroll
                for (int rt = 0; rt < 4; ++rt) {
                    acc[ci][rt] = __builtin_amdgcn_mfma_f32_16x16x32_bf16(ahi[rt], bh, acc[ci][rt], 0, 0, 0);
                    acc[ci][rt] = __builtin_amdgcn_mfma_f32_16x16x32_bf16(ahi[rt], bl, acc[ci][rt], 0, 0, 0);
                    acc[ci][rt] = __builtin_amdgcn_mfma_f32_16x16x32_bf16(alo[rt], bh, acc[ci][rt], 0, 0, 0);
                }
            }
        }
    }

    // ---- epilogue: 2 phases (row halves); stage 32 rows x 800 cols, then 1024 units ----
    float lad_total = 0.0f;   // kept per-phase, written per-phase

#pragma unroll
    for (int rhalf = 0; rhalf < 2; ++rhalf) {
        __syncthreads();                                        // p_lds region safe to (re)write
#pragma unroll
        for (int ci = 0; ci < 4; ++ci) {
            if (ci < nct) {
                const int ct = w + (ci << 4);
                const float bias = b2[(ct << 4) + arow];
                const int col = (ct << 4) + arow;               // 0..799
#pragma unroll
                for (int rr = 0; rr < 2; ++rr) {
                    const int rt = rhalf * 2 + rr;
                    const f32x4 v = acc[ci][rt];
                    const int rowl = (rr << 4) + (kgrp << 2);   // 0..31 (+reg)
                    p_lds[(rowl + 0) * 801 + col] = v[0] + bias;
                    p_lds[(rowl + 1) * 801 + col] = v[1] + bias;
                    p_lds[(rowl + 2) * 801 + col] = v[2] + bias;
                    p_lds[(rowl + 3) * 801 + col] = v[3] + bias;
                }
            }
        }
        __syncthreads();

        // one (row, d) per thread: 32 rows x 32 d = 1024 units
        {
            const int r_l = t >> 5;
            const int dl  = t & 31;
            const float* p = &p_lds[r_l * 801 + dl * 25];
            float pv[25];
#pragma unroll
            for (int j = 0; j < 25; ++j) pv[j] = p[j];

            float cw[9], ch[9], dd[9];
            {
                float mw = pv[0];
#pragma unroll
                for (int j = 1; j < 8; ++j) mw = fmaxf(mw, pv[j]);
                float e[8], sw = 0.f;
#pragma unroll
                for (int j = 0; j < 8; ++j) { e[j] = __expf(pv[j] - mw); sw += e[j]; }
                const float scale = 0.992f / sw;
                float run = 0.f;
                cw[0] = 0.f;
#pragma unroll
                for (int j = 0; j < 8; ++j) { run += 0.001f + e[j] * scale; cw[j + 1] = run; }
                const float icn = 1.0f / fmaxf(cw[8], 1e-12f);
#pragma unroll
                for (int j = 1; j <= 8; ++j) cw[j] *= icn;
            }
            {
                float mh = pv[8];
#pragma unroll
                for (int j = 1; j < 8; ++j) mh = fmaxf(mh, pv[8 + j]);
                float e[8], sh = 0.f;
#pragma unroll
                for (int j = 0; j < 8; ++j) { e[j] = __expf(pv[8 + j] - mh); sh += e[j]; }
                const float scale = 0.992f / sh;
                float run = 0.f;
                ch[0] = 0.f;
#pragma unroll
                for (int j = 0; j < 8; ++j) { run += 0.001f + e[j] * scale; ch[j + 1] = run; }
                const float icn = 1.0f / fmaxf(ch[8], 1e-12f);
#pragma unroll
                for (int j = 1; j <= 8; ++j) ch[j] *= icn;
            }
#pragma unroll
            for (int j = 0; j < 9; ++j) {
                const float u = pv[16 + j];
                dd[j] = 0.001f + fmaxf(u, 0.f) + __logf(1.0f + __expf(-fabsf(u)));
            }

            const int grow = row0 + rhalf * 32 + r_l;
            const float x = inp[(size_t)grow * 64 + 32 + dl];
            const float xs = fminf(fmaxf((x + 10.0f) * 0.05f, 0.f), 1.f);
            int b = 0;
#pragma unroll
            for (int j = 1; j <= 8; ++j) b += (xs >= cw[j]) ? 1 : 0;
            b = min(b, 7);

            float xk = 0.f, wk = 0.f, yk = 0.f, hk = 0.f, dk = 0.f, dk1 = 0.f;
#pragma unroll
            for (int j = 0; j < 8; ++j) {
                if (b == j) {
                    xk = cw[j]; wk = cw[j + 1] - cw[j];
                    yk = ch[j]; hk = ch[j + 1] - ch[j];
                    dk = dd[j]; dk1 = dd[j + 1];
                }
            }

            const float EPSf = 1e-12f;
            const float tt = fminf(fmaxf((xs - xk) / (wk + EPSf), 0.f), 1.f);
            const float a = (hk + EPSf) / (wk + EPSf);
            const float omt = 1.f - tt;
            const float tomt = tt * omt;
            const float num = a * tt * tt + dk * tomt;
            const float den = a + (dk + dk1 - 2.f * a) * tomt;
            const float sres = num / (den + EPSf);
            const float ys = yk + hk * sres;
            float y = ys * 20.0f - 10.0f;
            const float dnum = a * a * (dk1 * tt * tt + 2.f * a * tomt + dk * omt * omt);
            const float dydx = dnum / (den * den + EPSf);
            float lad = __logf(fmaxf(dydx, 1e-12f));

            const bool inside = (x >= -10.0f) && (x <= 10.0f);
            if (!inside) { y = x; lad = 0.0f; }

            out[(size_t)grow * 64 + 32 + dl] = y;

            // reduce 32 d-lanes of this row (each 32-lane half of the wave = one row)
            float s = lad;
            s += __shfl_xor(s, 1, 64);
            s += __shfl_xor(s, 2, 64);
            s += __shfl_xor(s, 4, 64);
            s += __shfl_xor(s, 8, 64);
            s += __shfl_xor(s, 16, 64);
            if ((lane & 31) == 0) out[(size_t)NROWS * 64 + grow] = s;
            lad_total += s;   // keep alive (unused further; cheap)
        }
    }
    (void)lad_total;
}

extern "C" void kernel_launch(void* const* d_in, const int* in_sizes, int n_in,
                              void* d_out, int out_size, void* d_ws, size_t ws_size,
                              hipStream_t stream) {
    const float* inp = (const float*)d_in[0];
    const float* W1  = (const float*)d_in[1];
    const float* b1  = (const float*)d_in[2];
    const float* W2  = (const float*)d_in[3];
    const float* b2  = (const float*)d_in[4];
    float* out = (float*)d_out;
    short* wsp = (short*)d_ws;      // 819200 B for W2 hi/lo paired fragments

    static bool attr_done = false;
    if (!attr_done) {
        hipFuncSetAttribute((const void*)rqs_fused,
                            hipFuncAttributeMaxDynamicSharedMemorySize, LDS_TOTAL);
        attr_done = true;
    }

    hipLaunchKernelGGL(prep_w2, dim3(100), dim3(256), 0, stream, W2, wsp);
    hipLaunchKernelGGL(rqs_fused, dim3(NBLOCKS), dim3(NTHREADS), LDS_TOTAL, stream,
                       inp, W1, b1, (const short*)wsp, b2, out);
}

// Round 7
// 297.734 us; speedup vs baseline: 1.3744x; 1.0228x over previous
//
#include <hip/hip_runtime.h>
#include <math.h>

#define NROWS 131072
#define HID 256
#define NPAR 800
#define MROWS 32
#define NTHREADS 512
#define NBLOCKS (NROWS / MROWS)      // 4096

#define W2F_FRAGS 25600              // 50 col-tiles * 8 k-steps * 64 lanes
#define LDS_HLO 16384
#define LDS_X   32768
#define LDS_PLD 804                  // padded leading dim for p_lds
#define LDS_TOTAL (16 * LDS_PLD * 4) // 51456; p_lds[16][804] overlays hhi/hlo/x

typedef __attribute__((ext_vector_type(8))) short s16x8;
typedef __attribute__((ext_vector_type(4))) float f32x4;

__device__ __forceinline__ unsigned short bf16_rne(float f) {
    unsigned u = __float_as_uint(f);
    u += 0x7fffu + ((u >> 16) & 1u);
    return (unsigned short)(u >> 16);
}

// Pre-split W2 (fp32 [256][800]) into bf16 hi/lo fragments, hi/lo PAIRED per lane
// (32B contiguous per lane) in per-lane MFMA B-operand order:
//   pair g = ct*8+k0; lane l holds 8 bf16 = W2[k0*32 + (l>>4)*8 + j][ct*16 + (l&15)]
//   hi at s16x8 index g*128 + l*2, lo at g*128 + l*2 + 1
__global__ void prep_w2(const float* __restrict__ W2, short* __restrict__ wsp)
{
    const int t = blockIdx.x * 256 + threadIdx.x;
    if (t >= W2F_FRAGS) return;
    const int l = t & 63;
    const int g = t >> 6;
    const int ct = g >> 3, k0 = g & 7;
    const int c  = (ct << 4) + (l & 15);
    const int kb = (k0 << 5) + ((l >> 4) << 3);
    s16x8 hi, lo;
#pragma unroll
    for (int j = 0; j < 8; ++j) {
        float v = W2[(size_t)(kb + j) * NPAR + c];
        unsigned short h = bf16_rne(v);
        float hf = __uint_as_float((unsigned)h << 16);
        unsigned short lw = bf16_rne(v - hf);
        hi[j] = (short)h;
        lo[j] = (short)lw;
    }
    ((s16x8*)wsp)[g * 128 + l * 2]     = hi;
    ((s16x8*)wsp)[g * 128 + l * 2 + 1] = lo;
}

__global__ __launch_bounds__(NTHREADS, 4)
void rqs_fused(const float* __restrict__ inp,
               const float* __restrict__ W1,
               const float* __restrict__ b1,
               const short* __restrict__ W2F,
               const float* __restrict__ b2,
               float* __restrict__ out)
{
    extern __shared__ char smem[];
    char*  hhi   = smem;                       // [32][256] bf16, XOR-swizzled (16 KB)
    char*  hlo   = smem + LDS_HLO;             // [32][256] bf16, XOR-swizzled (16 KB)
    float* x_lds = (float*)(smem + LDS_X);     // [32][32] fp32 x_id (4 KB)
    float* p_lds = (float*)smem;               // [16][804] fp32, overlays (h,x dead by then)

    const int t    = threadIdx.x;
    const int row0 = blockIdx.x * MROWS;
    const int lane = t & 63;
    const int w    = t >> 6;                   // wave id 0..7
    const int arow = lane & 15;
    const int kgrp = lane >> 4;
    const int lane2 = lane << 1;

    const s16x8* BF = (const s16x8*)W2F;

    // wave w owns ct = w + 8*ci, ci=0..nct-1; nct = 7 for w<2 else 6 (max ct=49, no wrap)
    const int nct = (w < 2) ? 7 : 6;

    // ---- identity pass-through + x_id -> LDS: 32 rows x 8 float4 (256 units) ----
    if (t < 256) {
        const int r = t >> 3, q = t & 7;
        const float4 v = ((const float4*)(inp + (size_t)(row0 + r) * 64))[q];
        ((float4*)(out + (size_t)(row0 + r) * 64))[q] = v;
        ((float4*)(x_lds + r * 32))[q] = v;
    }
    __syncthreads();

    // ---- GEMM1: h = relu(x_id @ W1 + b1); split to bf16 hi/lo in LDS ----
    {
        const int j = t & 255;                                   // hidden col
        const int q = t >> 8;                                    // row half (wave-uniform)
        float w1v[32];
#pragma unroll
        for (int k = 0; k < 32; ++k) w1v[k] = W1[k * HID + j];
        const float bj = b1[j];
        for (int rr = 0; rr < 16; ++rr) {
            const int r = q * 16 + rr;
            const float4* xr = (const float4*)(x_lds + r * 32);  // uniform -> broadcast
            float s0 = bj, s1 = 0.f, s2 = 0.f, s3 = 0.f;
#pragma unroll
            for (int qq = 0; qq < 8; ++qq) {
                const float4 xv = xr[qq];
                s0 = fmaf(xv.x, w1v[4 * qq + 0], s0);
                s1 = fmaf(xv.y, w1v[4 * qq + 1], s1);
                s2 = fmaf(xv.z, w1v[4 * qq + 2], s2);
                s3 = fmaf(xv.w, w1v[4 * qq + 3], s3);
            }
            const float s = fmaxf((s0 + s1) + (s2 + s3), 0.0f);
            unsigned short hs = bf16_rne(s);
            float hf = __uint_as_float((unsigned)hs << 16);
            unsigned short ls = bf16_rne(s - hf);
            int byte = (r << 9) + (j << 1);
            byte ^= (r & 7) << 4;                                // bank swizzle
            *(short*)(hhi + byte) = (short)hs;
            *(short*)(hlo + byte) = (short)ls;
        }
    }
    __syncthreads();

    // ---- GEMM2: 3-term bf16 split (hi*hi + hi*lo + lo*hi), acc[7][2] ----
    f32x4 acc[7][2];
#pragma unroll
    for (int ci = 0; ci < 7; ++ci) {
        acc[ci][0] = (f32x4){0.f, 0.f, 0.f, 0.f};
        acc[ci][1] = (f32x4){0.f, 0.f, 0.f, 0.f};
    }

#pragma unroll 1
    for (int k0 = 0; k0 < 8; ++k0) {
        s16x8 ahi[2], alo[2];
#pragma unroll
        for (int rt = 0; rt < 2; ++rt) {
            const int row = rt * 16 + arow;
            int byte = (row << 9) + (k0 << 6) + (kgrp << 4);
            byte ^= (row & 7) << 4;
            ahi[rt] = *(const s16x8*)(hhi + byte);
            alo[rt] = *(const s16x8*)(hlo + byte);
        }
#pragma unroll
        for (int ci = 0; ci < 7; ++ci) {
            if (ci < nct) {
                const int ct = w + (ci << 3);                    // max 49
                const int f  = (ct * 8 + k0) * 128 + lane2;
                const s16x8 bh = BF[f];
                const s16x8 bl = BF[f + 1];
                __builtin_amdgcn_s_setprio(1);
                acc[ci][0] = __builtin_amdgcn_mfma_f32_16x16x32_bf16(ahi[0], bh, acc[ci][0], 0, 0, 0);
                acc[ci][1] = __builtin_amdgcn_mfma_f32_16x16x32_bf16(ahi[1], bh, acc[ci][1], 0, 0, 0);
                acc[ci][0] = __builtin_amdgcn_mfma_f32_16x16x32_bf16(ahi[0], bl, acc[ci][0], 0, 0, 0);
                acc[ci][1] = __builtin_amdgcn_mfma_f32_16x16x32_bf16(ahi[1], bl, acc[ci][1], 0, 0, 0);
                acc[ci][0] = __builtin_amdgcn_mfma_f32_16x16x32_bf16(alo[0], bh, acc[ci][0], 0, 0, 0);
                acc[ci][1] = __builtin_amdgcn_mfma_f32_16x16x32_bf16(alo[1], bh, acc[ci][1], 0, 0, 0);
                __builtin_amdgcn_s_setprio(0);
            }
        }
    }

    // ---- epilogue: 2 phases (row halves of 16); stage 16 x 800, then 512 units ----
#pragma unroll
    for (int rhalf = 0; rhalf < 2; ++rhalf) {
        __syncthreads();                                        // p_lds safe to (re)write
#pragma unroll
        for (int ci = 0; ci < 7; ++ci) {
            if (ci < nct) {
                const int ct = w + (ci << 3);
                const float bias = b2[(ct << 4) + arow];
                const int col = (ct << 4) + arow;               // 0..799
                const f32x4 v = acc[ci][rhalf];
                const int rowl = kgrp << 2;                     // 0..12 (+reg)
                p_lds[(rowl + 0) * LDS_PLD + col] = v[0] + bias;
                p_lds[(rowl + 1) * LDS_PLD + col] = v[1] + bias;
                p_lds[(rowl + 2) * LDS_PLD + col] = v[2] + bias;
                p_lds[(rowl + 3) * LDS_PLD + col] = v[3] + bias;
            }
        }
        __syncthreads();

        // one (row, d) per thread: 16 rows x 32 d = 512 units
        {
            const int r_l = t >> 5;
            const int dl  = t & 31;
            const float* p = &p_lds[r_l * LDS_PLD + dl * 25];
            float pv[25];
#pragma unroll
            for (int j = 0; j < 25; ++j) pv[j] = p[j];

            float cw[9], ch[9], dd[9];
            {
                float mw = pv[0];
#pragma unroll
                for (int j = 1; j < 8; ++j) mw = fmaxf(mw, pv[j]);
                float e[8], sw = 0.f;
#pragma unroll
                for (int j = 0; j < 8; ++j) { e[j] = __expf(pv[j] - mw); sw += e[j]; }
                const float scale = 0.992f / sw;
                float run = 0.f;
                cw[0] = 0.f;
#pragma unroll
                for (int j = 0; j < 8; ++j) { run += 0.001f + e[j] * scale; cw[j + 1] = run; }
                const float icn = 1.0f / fmaxf(cw[8], 1e-12f);
#pragma unroll
                for (int j = 1; j <= 8; ++j) cw[j] *= icn;
            }
            {
                float mh = pv[8];
#pragma unroll
                for (int j = 1; j < 8; ++j) mh = fmaxf(mh, pv[8 + j]);
                float e[8], sh = 0.f;
#pragma unroll
                for (int j = 0; j < 8; ++j) { e[j] = __expf(pv[8 + j] - mh); sh += e[j]; }
                const float scale = 0.992f / sh;
                float run = 0.f;
                ch[0] = 0.f;
#pragma unroll
                for (int j = 0; j < 8; ++j) { run += 0.001f + e[j] * scale; ch[j + 1] = run; }
                const float icn = 1.0f / fmaxf(ch[8], 1e-12f);
#pragma unroll
                for (int j = 1; j <= 8; ++j) ch[j] *= icn;
            }
#pragma unroll
            for (int j = 0; j < 9; ++j) {
                const float u = pv[16 + j];
                dd[j] = 0.001f + fmaxf(u, 0.f) + __logf(1.0f + __expf(-fabsf(u)));
            }

            const int grow = row0 + rhalf * 16 + r_l;
            const float x = inp[(size_t)grow * 64 + 32 + dl];
            const float xs = fminf(fmaxf((x + 10.0f) * 0.05f, 0.f), 1.f);
            int b = 0;
#pragma unroll
            for (int j = 1; j <= 8; ++j) b += (xs >= cw[j]) ? 1 : 0;
            b = min(b, 7);

            float xk = 0.f, wk = 0.f, yk = 0.f, hk = 0.f, dk = 0.f, dk1 = 0.f;
#pragma unroll
            for (int j = 0; j < 8; ++j) {
                if (b == j) {
                    xk = cw[j]; wk = cw[j + 1] - cw[j];
                    yk = ch[j]; hk = ch[j + 1] - ch[j];
                    dk = dd[j]; dk1 = dd[j + 1];
                }
            }

            const float EPSf = 1e-12f;
            const float tt = fminf(fmaxf((xs - xk) / (wk + EPSf), 0.f), 1.f);
            const float a = (hk + EPSf) / (wk + EPSf);
            const float omt = 1.f - tt;
            const float tomt = tt * omt;
            const float num = a * tt * tt + dk * tomt;
            const float den = a + (dk + dk1 - 2.f * a) * tomt;
            const float sres = num / (den + EPSf);
            const float ys = yk + hk * sres;
            float y = ys * 20.0f - 10.0f;
            const float dnum = a * a * (dk1 * tt * tt + 2.f * a * tomt + dk * omt * omt);
            const float dydx = dnum / (den * den + EPSf);
            float lad = __logf(fmaxf(dydx, 1e-12f));

            const bool inside = (x >= -10.0f) && (x <= 10.0f);
            if (!inside) { y = x; lad = 0.0f; }

            out[(size_t)grow * 64 + 32 + dl] = y;

            // reduce 32 d-lanes of this row (each 32-lane half-wave = one row)
            float s = lad;
            s += __shfl_xor(s, 1, 64);
            s += __shfl_xor(s, 2, 64);
            s += __shfl_xor(s, 4, 64);
            s += __shfl_xor(s, 8, 64);
            s += __shfl_xor(s, 16, 64);
            if ((lane & 31) == 0) out[(size_t)NROWS * 64 + grow] = s;
        }
    }
}

extern "C" void kernel_launch(void* const* d_in, const int* in_sizes, int n_in,
                              void* d_out, int out_size, void* d_ws, size_t ws_size,
                              hipStream_t stream) {
    const float* inp = (const float*)d_in[0];
    const float* W1  = (const float*)d_in[1];
    const float* b1  = (const float*)d_in[2];
    const float* W2  = (const float*)d_in[3];
    const float* b2  = (const float*)d_in[4];
    float* out = (float*)d_out;
    short* wsp = (short*)d_ws;      // 819200 B for W2 hi/lo paired fragments

    hipLaunchKernelGGL(prep_w2, dim3(100), dim3(256), 0, stream, W2, wsp);
    hipLaunchKernelGGL(rqs_fused, dim3(NBLOCKS), dim3(NTHREADS), LDS_TOTAL, stream,
                       inp, W1, b1, (const short*)wsp, b2, out);
}

// Round 8
// 268.460 us; speedup vs baseline: 1.5243x; 1.1090x over previous
//
#include <hip/hip_runtime.h>
#include <math.h>

#define NROWS 131072
#define HID 256
#define NPAR 800
#define MROWS 32
#define NTHREADS 512
#define NBLOCKS (NROWS / MROWS)      // 4096

#define W2F_FRAGS 25600              // 50 col-tiles * 8 k-steps * 64 lanes
#define W1F_BASE  51200              // s16x8 units: after W2F hi/lo pairs
#define LDS_HLO 16384
#define LDS_X   32768
#define LDS_PLD 804                  // padded leading dim for p_lds
#define LDS_TOTAL (16 * LDS_PLD * 4) // 51456; p_lds[16][804] overlays hhi/hlo/x

typedef __attribute__((ext_vector_type(8))) short s16x8;
typedef __attribute__((ext_vector_type(4))) float f32x4;

__device__ __forceinline__ unsigned short bf16_rne(float f) {
    unsigned u = __float_as_uint(f);
    u += 0x7fffu + ((u >> 16) & 1u);
    return (unsigned short)(u >> 16);
}
__device__ __forceinline__ float bf16_to_f(unsigned short h) {
    return __uint_as_float((unsigned)h << 16);
}

// Pre-split W2 (fp32 [256][800]) and W1 (fp32 [32][256]) into bf16 hi/lo fragment
// pairs in per-lane MFMA B-operand order (hi/lo PAIRED, 32B contiguous per lane):
//   W2: pair g = ct*8+k0; lane l: 8 bf16 = W2[k0*32+(l>>4)*8+j][ct*16+(l&15)]
//       hi at s16x8 index g*128 + l*2, lo at +1
//   W1: ct in [0,16); lane l: 8 bf16 = W1[(l>>4)*8+j][ct*16+(l&15)]
//       hi at W1F_BASE + ct*128 + l*2, lo at +1
__global__ void prep_w(const float* __restrict__ W2, const float* __restrict__ W1,
                       short* __restrict__ wsp)
{
    const int t = blockIdx.x * 256 + threadIdx.x;
    if (t < W2F_FRAGS) {
        const int l = t & 63;
        const int g = t >> 6;
        const int ct = g >> 3, k0 = g & 7;
        const int c  = (ct << 4) + (l & 15);
        const int kb = (k0 << 5) + ((l >> 4) << 3);
        s16x8 hi, lo;
#pragma unroll
        for (int j = 0; j < 8; ++j) {
            float v = W2[(size_t)(kb + j) * NPAR + c];
            unsigned short h = bf16_rne(v);
            unsigned short lw = bf16_rne(v - bf16_to_f(h));
            hi[j] = (short)h;
            lo[j] = (short)lw;
        }
        ((s16x8*)wsp)[g * 128 + l * 2]     = hi;
        ((s16x8*)wsp)[g * 128 + l * 2 + 1] = lo;
    } else if (t < W2F_FRAGS + 1024) {
        const int t1 = t - W2F_FRAGS;
        const int l  = t1 & 63;
        const int ct = t1 >> 6;                 // 0..15
        const int c  = (ct << 4) + (l & 15);
        const int kb = (l >> 4) << 3;
        s16x8 hi, lo;
#pragma unroll
        for (int j = 0; j < 8; ++j) {
            float v = W1[(size_t)(kb + j) * HID + c];
            unsigned short h = bf16_rne(v);
            unsigned short lw = bf16_rne(v - bf16_to_f(h));
            hi[j] = (short)h;
            lo[j] = (short)lw;
        }
        ((s16x8*)wsp)[W1F_BASE + ct * 128 + l * 2]     = hi;
        ((s16x8*)wsp)[W1F_BASE + ct * 128 + l * 2 + 1] = lo;
    }
}

__global__ __launch_bounds__(NTHREADS, 4)
void rqs_fused(const float* __restrict__ inp,
               const float* __restrict__ b1,
               const short* __restrict__ W2F,
               const float* __restrict__ b2,
               float* __restrict__ out)
{
    extern __shared__ char smem[];
    char*  hhi   = smem;                       // [32][256] bf16, XOR-swizzled (16 KB)
    char*  hlo   = smem + LDS_HLO;             // [32][256] bf16, XOR-swizzled (16 KB)
    char*  x_c   = smem + LDS_X;               // [32][32] fp32 x_id, XOR-swizzled (4 KB)
    float* p_lds = (float*)smem;               // [16][804] fp32, overlays (h,x dead by then)

    const int t    = threadIdx.x;
    const int row0 = blockIdx.x * MROWS;
    const int lane = t & 63;
    const int w    = t >> 6;                   // wave id 0..7
    const int arow = lane & 15;
    const int kgrp = lane >> 4;
    const int lane2 = lane << 1;

    const s16x8* BF = (const s16x8*)W2F;

    // wave w owns ct = w + 8*ci, ci=0..nct-1; nct = 7 for w<2 else 6 (max ct=49)
    const int nct = (w < 2) ? 7 : 6;

    // ---- identity pass-through + x_id -> LDS (swizzled): 32 rows x 8 float4 ----
    if (t < 256) {
        const int r = t >> 3, q = t & 7;
        const float4 v = ((const float4*)(inp + (size_t)(row0 + r) * 64))[q];
        ((float4*)(out + (size_t)(row0 + r) * 64))[q] = v;
        int byte = (r << 7) + (q << 4);
        byte ^= (r & 7) << 4;                                    // bank swizzle
        *(float4*)(x_c + byte) = v;
    }
    __syncthreads();

    // ---- GEMM1 via MFMA: h = relu(x_id @ W1 + b1), 3-term bf16 split ----
    // wave w computes hidden col-tiles {2w, 2w+1} x row-tiles {0,1}
    {
        const int c0 = (2 * w) * 128 + W1F_BASE + lane2;
        const int c1 = (2 * w + 1) * 128 + W1F_BASE + lane2;
        const s16x8 w1h0 = BF[c0], w1l0 = BF[c0 + 1];
        const s16x8 w1h1 = BF[c1], w1l1 = BF[c1 + 1];

        s16x8 xhi[2], xlo[2];
#pragma unroll
        for (int rt = 0; rt < 2; ++rt) {
            const int row  = rt * 16 + arow;
            const int base = (row << 7) + (kgrp << 5);
            const int sw   = (row & 7) << 4;
            const float4 va = *(const float4*)(x_c + (base ^ sw));
            const float4 vb = *(const float4*)(x_c + ((base + 16) ^ sw));
            const float xv[8] = {va.x, va.y, va.z, va.w, vb.x, vb.y, vb.z, vb.w};
#pragma unroll
            for (int j = 0; j < 8; ++j) {
                unsigned short h = bf16_rne(xv[j]);
                xhi[rt][j] = (short)h;
                xlo[rt][j] = (short)bf16_rne(xv[j] - bf16_to_f(h));
            }
        }

        const float bias0 = b1[(2 * w) * 16 + arow];
        const float bias1 = b1[(2 * w + 1) * 16 + arow];
        f32x4 g[2][2];
        g[0][0] = (f32x4){bias0, bias0, bias0, bias0};
        g[1][0] = (f32x4){bias0, bias0, bias0, bias0};
        g[0][1] = (f32x4){bias1, bias1, bias1, bias1};
        g[1][1] = (f32x4){bias1, bias1, bias1, bias1};

#pragma unroll
        for (int rt = 0; rt < 2; ++rt) {
            g[rt][0] = __builtin_amdgcn_mfma_f32_16x16x32_bf16(xhi[rt], w1h0, g[rt][0], 0, 0, 0);
            g[rt][1] = __builtin_amdgcn_mfma_f32_16x16x32_bf16(xhi[rt], w1h1, g[rt][1], 0, 0, 0);
            g[rt][0] = __builtin_amdgcn_mfma_f32_16x16x32_bf16(xhi[rt], w1l0, g[rt][0], 0, 0, 0);
            g[rt][1] = __builtin_amdgcn_mfma_f32_16x16x32_bf16(xhi[rt], w1l1, g[rt][1], 0, 0, 0);
            g[rt][0] = __builtin_amdgcn_mfma_f32_16x16x32_bf16(xlo[rt], w1h0, g[rt][0], 0, 0, 0);
            g[rt][1] = __builtin_amdgcn_mfma_f32_16x16x32_bf16(xlo[rt], w1h1, g[rt][1], 0, 0, 0);
        }

        // relu + bf16 hi/lo split + write to hhi/hlo (same layout GEMM2 reads)
#pragma unroll
        for (int rt = 0; rt < 2; ++rt) {
#pragma unroll
            for (int ci = 0; ci < 2; ++ci) {
                const int col = (2 * w + ci) * 16 + arow;
#pragma unroll
                for (int i = 0; i < 4; ++i) {
                    const int row = rt * 16 + (kgrp << 2) + i;
                    const float s = fmaxf(g[rt][ci][i], 0.0f);
                    unsigned short hs = bf16_rne(s);
                    unsigned short ls = bf16_rne(s - bf16_to_f(hs));
                    int byte = (row << 9) + (col << 1);
                    byte ^= (row & 7) << 4;
                    *(short*)(hhi + byte) = (short)hs;
                    *(short*)(hlo + byte) = (short)ls;
                }
            }
        }
    }
    __syncthreads();

    // ---- GEMM2: 3-term bf16 split (hi*hi + hi*lo + lo*hi), acc[7][2] ----
    f32x4 acc[7][2];
#pragma unroll
    for (int ci = 0; ci < 7; ++ci) {
        acc[ci][0] = (f32x4){0.f, 0.f, 0.f, 0.f};
        acc[ci][1] = (f32x4){0.f, 0.f, 0.f, 0.f};
    }

#pragma unroll 1
    for (int k0 = 0; k0 < 8; ++k0) {
        s16x8 ahi[2], alo[2];
#pragma unroll
        for (int rt = 0; rt < 2; ++rt) {
            const int row = rt * 16 + arow;
            int byte = (row << 9) + (k0 << 6) + (kgrp << 4);
            byte ^= (row & 7) << 4;
            ahi[rt] = *(const s16x8*)(hhi + byte);
            alo[rt] = *(const s16x8*)(hlo + byte);
        }
#pragma unroll
        for (int ci = 0; ci < 7; ++ci) {
            if (ci < nct) {
                const int ct = w + (ci << 3);                    // max 49
                const int f  = (ct * 8 + k0) * 128 + lane2;
                const s16x8 bh = BF[f];
                const s16x8 bl = BF[f + 1];
                __builtin_amdgcn_s_setprio(1);
                acc[ci][0] = __builtin_amdgcn_mfma_f32_16x16x32_bf16(ahi[0], bh, acc[ci][0], 0, 0, 0);
                acc[ci][1] = __builtin_amdgcn_mfma_f32_16x16x32_bf16(ahi[1], bh, acc[ci][1], 0, 0, 0);
                acc[ci][0] = __builtin_amdgcn_mfma_f32_16x16x32_bf16(ahi[0], bl, acc[ci][0], 0, 0, 0);
                acc[ci][1] = __builtin_amdgcn_mfma_f32_16x16x32_bf16(ahi[1], bl, acc[ci][1], 0, 0, 0);
                acc[ci][0] = __builtin_amdgcn_mfma_f32_16x16x32_bf16(alo[0], bh, acc[ci][0], 0, 0, 0);
                acc[ci][1] = __builtin_amdgcn_mfma_f32_16x16x32_bf16(alo[1], bh, acc[ci][1], 0, 0, 0);
                __builtin_amdgcn_s_setprio(0);
            }
        }
    }

    // ---- epilogue: 2 phases (row halves of 16); stage 16 x 800, then 512 units ----
#pragma unroll
    for (int rhalf = 0; rhalf < 2; ++rhalf) {
        __syncthreads();                                        // p_lds safe to (re)write
#pragma unroll
        for (int ci = 0; ci < 7; ++ci) {
            if (ci < nct) {
                const int ct = w + (ci << 3);
                const float bias = b2[(ct << 4) + arow];
                const int col = (ct << 4) + arow;               // 0..799
                const f32x4 v = acc[ci][rhalf];
                const int rowl = kgrp << 2;                     // 0..12 (+reg)
                p_lds[(rowl + 0) * LDS_PLD + col] = v[0] + bias;
                p_lds[(rowl + 1) * LDS_PLD + col] = v[1] + bias;
                p_lds[(rowl + 2) * LDS_PLD + col] = v[2] + bias;
                p_lds[(rowl + 3) * LDS_PLD + col] = v[3] + bias;
            }
        }
        __syncthreads();

        // one (row, d) per thread: 16 rows x 32 d = 512 units
        {
            const int r_l = t >> 5;
            const int dl  = t & 31;
            const float* p = &p_lds[r_l * LDS_PLD + dl * 25];
            float pv[25];
#pragma unroll
            for (int j = 0; j < 25; ++j) pv[j] = p[j];

            float cw[9], ch[9];
            {
                float mw = pv[0];
#pragma unroll
                for (int j = 1; j < 8; ++j) mw = fmaxf(mw, pv[j]);
                float e[8], sw = 0.f;
#pragma unroll
                for (int j = 0; j < 8; ++j) { e[j] = __expf(pv[j] - mw); sw += e[j]; }
                const float scale = 0.992f / sw;
                float run = 0.f;
                cw[0] = 0.f;
#pragma unroll
                for (int j = 0; j < 8; ++j) { run += 0.001f + e[j] * scale; cw[j + 1] = run; }
                const float icn = 1.0f / fmaxf(cw[8], 1e-12f);
#pragma unroll
                for (int j = 1; j <= 8; ++j) cw[j] *= icn;
            }
            {
                float mh = pv[8];
#pragma unroll
                for (int j = 1; j < 8; ++j) mh = fmaxf(mh, pv[8 + j]);
                float e[8], sh = 0.f;
#pragma unroll
                for (int j = 0; j < 8; ++j) { e[j] = __expf(pv[8 + j] - mh); sh += e[j]; }
                const float scale = 0.992f / sh;
                float run = 0.f;
                ch[0] = 0.f;
#pragma unroll
                for (int j = 0; j < 8; ++j) { run += 0.001f + e[j] * scale; ch[j + 1] = run; }
                const float icn = 1.0f / fmaxf(ch[8], 1e-12f);
#pragma unroll
                for (int j = 1; j <= 8; ++j) ch[j] *= icn;
            }

            const int grow = row0 + rhalf * 16 + r_l;
            const float x = inp[(size_t)grow * 64 + 32 + dl];
            const float xs = fminf(fmaxf((x + 10.0f) * 0.05f, 0.f), 1.f);
            int b = 0;
#pragma unroll
            for (int j = 1; j <= 8; ++j) b += (xs >= cw[j]) ? 1 : 0;
            b = min(b, 7);

            float xk = 0.f, wk = 0.f, yk = 0.f, hk = 0.f;
#pragma unroll
            for (int j = 0; j < 8; ++j) {
                if (b == j) {
                    xk = cw[j]; wk = cw[j + 1] - cw[j];
                    yk = ch[j]; hk = ch[j + 1] - ch[j];
                }
            }
            // softplus only on the selected pair d[b], d[b+1]
            float ud0 = pv[16], ud1 = pv[17];
#pragma unroll
            for (int j = 1; j < 8; ++j) {
                const bool ge = (b >= j);
                ud0 = ge ? pv[16 + j] : ud0;
                ud1 = ge ? pv[17 + j] : ud1;
            }
            const float dk  = 0.001f + fmaxf(ud0, 0.f) + __logf(1.0f + __expf(-fabsf(ud0)));
            const float dk1 = 0.001f + fmaxf(ud1, 0.f) + __logf(1.0f + __expf(-fabsf(ud1)));

            const float EPSf = 1e-12f;
            const float tt = fminf(fmaxf((xs - xk) / (wk + EPSf), 0.f), 1.f);
            const float a = (hk + EPSf) / (wk + EPSf);
            const float omt = 1.f - tt;
            const float tomt = tt * omt;
            const float num = a * tt * tt + dk * tomt;
            const float den = a + (dk + dk1 - 2.f * a) * tomt;
            const float sres = num / (den + EPSf);
            const float ys = yk + hk * sres;
            float y = ys * 20.0f - 10.0f;
            const float dnum = a * a * (dk1 * tt * tt + 2.f * a * tomt + dk * omt * omt);
            const float dydx = dnum / (den * den + EPSf);
            float lad = __logf(fmaxf(dydx, 1e-12f));

            const bool inside = (x >= -10.0f) && (x <= 10.0f);
            if (!inside) { y = x; lad = 0.0f; }

            out[(size_t)grow * 64 + 32 + dl] = y;

            // reduce 32 d-lanes of this row (each 32-lane half-wave = one row)
            float s = lad;
            s += __shfl_xor(s, 1, 64);
            s += __shfl_xor(s, 2, 64);
            s += __shfl_xor(s, 4, 64);
            s += __shfl_xor(s, 8, 64);
            s += __shfl_xor(s, 16, 64);
            if ((lane & 31) == 0) out[(size_t)NROWS * 64 + grow] = s;
        }
    }
}

extern "C" void kernel_launch(void* const* d_in, const int* in_sizes, int n_in,
                              void* d_out, int out_size, void* d_ws, size_t ws_size,
                              hipStream_t stream) {
    const float* inp = (const float*)d_in[0];
    const float* W1  = (const float*)d_in[1];
    const float* b1  = (const float*)d_in[2];
    const float* W2  = (const float*)d_in[3];
    const float* b2  = (const float*)d_in[4];
    float* out = (float*)d_out;
    short* wsp = (short*)d_ws;      // 851968 B: W2F pairs + W1F pairs

    hipLaunchKernelGGL(prep_w, dim3(104), dim3(256), 0, stream, W2, W1, wsp);
    hipLaunchKernelGGL(rqs_fused, dim3(NBLOCKS), dim3(NTHREADS), LDS_TOTAL, stream,
                       inp, b1, (const short*)wsp, b2, out);
}